// Round 3
// baseline (269.659 us; speedup 1.0000x reference)
//
#include <hip/hip_runtime.h>
#include <hip/hip_cooperative_groups.h>

namespace cg = cooperative_groups;

typedef unsigned short u16;
typedef short bf16x8 __attribute__((ext_vector_type(8)));
typedef float f32x4 __attribute__((ext_vector_type(4)));

#define BB 8
#define CC 768
#define NN 256
#define HH 12
#define DD 64
#define BCN 196608       // C*N per batch
#define SCALE 0.125f
#define LDP 72           // LDS pitch (u16): 144B rows, 16B-aligned, 2-way banks only
#define BUFB 9216        // one 64xLDP u16 buffer in bytes

__device__ __forceinline__ u16 f2b(float f) {
    union { float f; unsigned int i; } v; v.f = f;
    unsigned int r = v.i + 0x7FFFu + ((v.i >> 16) & 1u);
    return (u16)(r >> 16);
}

// one 64x64x64 MFMA macro-step (4 waves, each 32x32, K=64 in two k-halves)
#define MFMA8(ASP, BSP, ACC)                                                              \
    _Pragma("unroll")                                                                     \
    for (int kk = 0; kk < 2; ++kk) {                                                      \
        bf16x8 a0 = *reinterpret_cast<bf16x8*>((ASP) + (wm + tx) * LDP + kk * 32 + q * 8);\
        bf16x8 a1 = *reinterpret_cast<bf16x8*>((ASP) + (wm + 16 + tx) * LDP + kk * 32 + q * 8);\
        bf16x8 b0 = *reinterpret_cast<bf16x8*>((BSP) + (wn + tx) * LDP + kk * 32 + q * 8);\
        bf16x8 b1 = *reinterpret_cast<bf16x8*>((BSP) + (wn + 16 + tx) * LDP + kk * 32 + q * 8);\
        ACC[0][0] = __builtin_amdgcn_mfma_f32_16x16x32_bf16(a0, b0, ACC[0][0], 0, 0, 0);  \
        ACC[0][1] = __builtin_amdgcn_mfma_f32_16x16x32_bf16(a0, b1, ACC[0][1], 0, 0, 0);  \
        ACC[1][0] = __builtin_amdgcn_mfma_f32_16x16x32_bf16(a1, b0, ACC[1][0], 0, 0, 0);  \
        ACC[1][1] = __builtin_amdgcn_mfma_f32_16x16x32_bf16(a1, b1, ACC[1][1], 0, 0, 0);  \
    }

// ---------------------------------------------------------------------------
// Single cooperative kernel, 384 blocks x 256 threads, 3 grid syncs.
// LDS arena (36864 B, 2 blocks/CU = 73.7 KB <= 160 KB):
//   phase A/B:  As = [0, 9216)   Bs = [9216, 18432)   T(f32 64x68) = [18432, 35840)
//   phase C:    A-dbuf = [cur*9216)   B-dbuf = [18432 + cur*9216)
//   Z: blocks bid%48==0 zero G[b]                        (published by sync 1)
//   A: (h, n-chunk, b) fused proj+gram -> atomicAdd G    (12h x 4n x 8b = 384)
//      [sync 1 sits between A's MFMAs and its atomics: all blocks arrive together]
//   B: U[b][m][dd] = sum_d x^T[m][d] G[dd][d]            (48m x 8b = 384)
//   C: out = x + bd + Wd . U2^T  (dbuf + reg-prefetch)   (4n x 12o x 8b = 384)
// Cross-XCD visibility of G/U via grid.sync() agent-scope acq-rel fences.
// ---------------------------------------------------------------------------
__global__ __launch_bounds__(256, 2) void k_all(
    const float* __restrict__ Wp, const float* __restrict__ cross,
    const float* __restrict__ bp, const float* __restrict__ x,
    const float* __restrict__ Wd, const float* __restrict__ bd,
    u16* __restrict__ U, float* __restrict__ G, float* __restrict__ out)
{
    __shared__ __align__(16) unsigned char smem[4 * BUFB];
    cg::grid_group grid = cg::this_grid();

    const int bid = blockIdx.x;
    const int t = threadIdx.x;
    const int lane = t & 63, wave = t >> 6;
    const int q = lane >> 4, tx = lane & 15;
    const int wm = (wave & 1) * 32, wn = (wave >> 1) * 32;
    const int r4 = t >> 2, cq = t & 3;
    const int b = bid / 48;                 // all three phases use 48 blocks/batch

    // ---- Phase Z: zero G[b] (one block per batch) ----
    if ((bid % 48) == 0) {
        float4 z = {0.f, 0.f, 0.f, 0.f};
        float* Gb = G + b * 4096;
        #pragma unroll
        for (int j = 0; j < 4; ++j)
            *reinterpret_cast<float4*>(Gb + t * 4 + j * 1024) = z;
    }

    // ---- Phase A: fused proj+gram ----
    {
        const int h  = bid % 12;
        const int n0 = ((bid / 12) % 4) * 64;
        const float* crb = cross + b * BCN;
        const float* wrow = Wp + (r4 * HH + h) * CC;    // Wp_h row dd=r4
        u16* Asp = (u16*)smem;
        u16* Bsp = (u16*)(smem + BUFB);
        float (*T)[68] = (float (*)[68])(smem + 2 * BUFB);   // 17408 <= 18432

        f32x4 acc[2][2] = {};
        float4 ra[4], rc[4];
        #pragma unroll
        for (int u = 0; u < 4; ++u) {
            const int cl = (cq + 4 * u) * 4;
            ra[u] = *reinterpret_cast<const float4*>(wrow + cl);
            rc[u] = *reinterpret_cast<const float4*>(crb + r4 * NN + n0 + cl);
        }
        for (int it = 0; it < 12; ++it) {
            if (it > 0) __syncthreads();
            {   // regs -> As (cvt) and T (f32)
                u16* dstA = Asp + r4 * LDP;
                #pragma unroll
                for (int u = 0; u < 4; ++u) {
                    const int cl = (cq + 4 * u) * 4;
                    ushort4 w; w.x = f2b(ra[u].x); w.y = f2b(ra[u].y);
                    w.z = f2b(ra[u].z); w.w = f2b(ra[u].w);
                    *reinterpret_cast<ushort4*>(dstA + cl) = w;
                    T[r4][cl + 0] = rc[u].x; T[r4][cl + 1] = rc[u].y;
                    T[r4][cl + 2] = rc[u].z; T[r4][cl + 3] = rc[u].w;
                }
            }
            if (it < 11) {   // next-iter global loads in flight across transpose+mfma
                const int c0 = (it + 1) * 64;
                #pragma unroll
                for (int u = 0; u < 4; ++u) {
                    const int cl = (cq + 4 * u) * 4;
                    ra[u] = *reinterpret_cast<const float4*>(wrow + c0 + cl);
                    rc[u] = *reinterpret_cast<const float4*>(crb + (c0 + r4) * NN + n0 + cl);
                }
            }
            __syncthreads();
            {   // Bs[n][c] = cvt(T[c][n])  (transpose; col reads 2-way = free)
                const int nn = t >> 2, dq = t & 3;
                u16* dst = Bsp + nn * LDP;
                #pragma unroll
                for (int u = 0; u < 4; ++u) {
                    const int c4 = (dq + 4 * u) * 4;
                    ushort4 w;
                    w.x = f2b(T[c4 + 0][nn]); w.y = f2b(T[c4 + 1][nn]);
                    w.z = f2b(T[c4 + 2][nn]); w.w = f2b(T[c4 + 3][nn]);
                    *reinterpret_cast<ushort4*>(dst + c4) = w;
                }
            }
            __syncthreads();
            MFMA8(Asp, Bsp, acc)
        }
        __syncthreads();
        // gram B operand: cross_h rows -> regs
        float4 rg[4];
        #pragma unroll
        for (int u = 0; u < 4; ++u)
            rg[u] = *reinterpret_cast<const float4*>(crb + (r4 * HH + h) * NN + n0 + (cq + 4 * u) * 4);
        // As2[dd][n] = bf16(cp_partial + bias)
        #pragma unroll
        for (int i = 0; i < 2; ++i)
            #pragma unroll
            for (int r = 0; r < 4; ++r) {
                const int ddl = wm + i * 16 + q * 4 + r;
                const float bias = bp[ddl * HH + h];
                #pragma unroll
                for (int j = 0; j < 2; ++j)
                    Asp[ddl * LDP + wn + j * 16 + tx] = f2b(acc[i][j][r] + bias);
            }
        {   // Bs2[dc][n] = bf16(cross_h)
            u16* dst = Bsp + r4 * LDP;
            #pragma unroll
            for (int u = 0; u < 4; ++u) {
                const int cl = (cq + 4 * u) * 4;
                ushort4 w; w.x = f2b(rg[u].x); w.y = f2b(rg[u].y);
                w.z = f2b(rg[u].z); w.w = f2b(rg[u].w);
                *reinterpret_cast<ushort4*>(dst + cl) = w;
            }
        }
        __syncthreads();
        f32x4 g[2][2] = {};
        MFMA8(Asp, Bsp, g)

        grid.sync();   // sync 1: publishes Z's zeros; all blocks arrive together

        float* Gb = G + b * 4096;
        #pragma unroll
        for (int i = 0; i < 2; ++i)
            #pragma unroll
            for (int j = 0; j < 2; ++j)
                #pragma unroll
                for (int r = 0; r < 4; ++r) {
                    const int dd = wm + i * 16 + q * 4 + r;   // cp-side (G col)
                    const int dc = wn + j * 16 + tx;          // cross-side (G row)
                    atomicAdd(Gb + dc * DD + dd, g[i][j][r] * SCALE);
                }
    }

    grid.sync();       // sync 2: G complete + visible

    // ---- Phase B: U[m][dd] = sum_d xT[m][d] G[dd][d] ----
    {
        const int m0 = (bid % 48) * 64;
        const int h = m0 >> 8, nn0 = m0 & 255;
        const float* xb = x + b * BCN;
        const float* Gb = G + b * 4096;
        u16* Asp = (u16*)smem;
        u16* Bsp = (u16*)(smem + BUFB);
        float (*T)[68] = (float (*)[68])(smem + 2 * BUFB);
        f32x4 acc[2][2] = {};
        {   // T[d][nl] = x[(d*12+h)*256 + nn0+nl]
            const float* src = xb + (r4 * HH + h) * NN + nn0;
            #pragma unroll
            for (int u = 0; u < 4; ++u) {
                const int nl = (cq + 4 * u) * 4;
                float4 v = *reinterpret_cast<const float4*>(src + nl);
                T[r4][nl + 0] = v.x; T[r4][nl + 1] = v.y;
                T[r4][nl + 2] = v.z; T[r4][nl + 3] = v.w;
            }
        }
        {   // Bs[dd][d] = cvt(G[dd][d])
            const float* src = Gb + r4 * DD;
            u16* dst = Bsp + r4 * LDP;
            #pragma unroll
            for (int u = 0; u < 4; ++u) {
                const int cl = (cq + 4 * u) * 4;
                float4 v = *reinterpret_cast<const float4*>(src + cl);
                ushort4 w; w.x = f2b(v.x); w.y = f2b(v.y); w.z = f2b(v.z); w.w = f2b(v.w);
                *reinterpret_cast<ushort4*>(dst + cl) = w;
            }
        }
        __syncthreads();
        {   // As[m_local][d] = cvt(T[d][m_local])
            const int nn = t >> 2, dq = t & 3;
            u16* dst = Asp + nn * LDP;
            #pragma unroll
            for (int u = 0; u < 4; ++u) {
                const int d4 = (dq + 4 * u) * 4;
                ushort4 w;
                w.x = f2b(T[d4 + 0][nn]); w.y = f2b(T[d4 + 1][nn]);
                w.z = f2b(T[d4 + 2][nn]); w.w = f2b(T[d4 + 3][nn]);
                *reinterpret_cast<ushort4*>(dst + d4) = w;
            }
        }
        __syncthreads();
        MFMA8(Asp, Bsp, acc)
        u16* Ub = U + b * BCN;
        #pragma unroll
        for (int i = 0; i < 2; ++i)
            #pragma unroll
            for (int j = 0; j < 2; ++j)
                #pragma unroll
                for (int r = 0; r < 4; ++r) {
                    const int m  = m0 + wm + i * 16 + q * 4 + r;
                    const int dd = wn + j * 16 + tx;
                    Ub[m * DD + dd] = f2b(acc[i][j][r]);
                }
    }

    grid.sync();       // sync 3: U complete + visible

    // ---- Phase C: out = x + bd + Wd . U2^T (dbuf LDS + reg prefetch) ----
    {
        const int n0 = (bid % 4) * 64;
        const int o0 = ((bid / 4) % 12) * 64;
        const int r8 = t >> 3, ch = (t & 7) * 8;
        const u16* Ub = U + b * BCN;
        float4 ra[4]; uint4 rb[2];

        auto loadit = [&](int it) {
            const int c0 = it * 64;
            const float* srcA = Wd + (o0 + r4) * CC + c0;
            #pragma unroll
            for (int u = 0; u < 4; ++u)
                ra[u] = *reinterpret_cast<const float4*>(srcA + (cq + 4 * u) * 4);
            rb[0] = *reinterpret_cast<const uint4*>(Ub + (n0 + r8) * CC + c0 + ch);
            rb[1] = *reinterpret_cast<const uint4*>(Ub + (n0 + r8 + 32) * CC + c0 + ch);
        };
        auto storeit = [&](int buf) {
            u16* dstA = (u16*)(smem + buf * BUFB) + r4 * LDP;
            #pragma unroll
            for (int u = 0; u < 4; ++u) {
                const int cl = (cq + 4 * u) * 4;
                ushort4 w; w.x = f2b(ra[u].x); w.y = f2b(ra[u].y);
                w.z = f2b(ra[u].z); w.w = f2b(ra[u].w);
                *reinterpret_cast<ushort4*>(dstA + cl) = w;
            }
            u16* dstB = (u16*)(smem + 2 * BUFB + buf * BUFB);
            *reinterpret_cast<uint4*>(dstB + r8 * LDP + ch) = rb[0];
            *reinterpret_cast<uint4*>(dstB + (r8 + 32) * LDP + ch) = rb[1];
        };

        f32x4 acc[2][2] = {};
        loadit(0);
        storeit(0);
        #pragma unroll 2
        for (int it = 0; it < 12; ++it) {
            const int cur = it & 1;
            if (it < 11) loadit(it + 1);       // in flight across barrier + MFMAs
            __syncthreads();
            u16* Asp = (u16*)(smem + cur * BUFB);
            u16* Bsp = (u16*)(smem + 2 * BUFB + cur * BUFB);
            MFMA8(Asp, Bsp, acc)
            if (it < 11) storeit(cur ^ 1);     // vmcnt wait lands after the MFMAs
        }
        #pragma unroll
        for (int i = 0; i < 2; ++i)
            #pragma unroll
            for (int j = 0; j < 2; ++j)
                #pragma unroll
                for (int r = 0; r < 4; ++r) {
                    const int o = o0 + wm + i * 16 + q * 4 + r;
                    const int n = n0 + wn + j * 16 + tx;
                    const int idx = b * BCN + o * NN + n;
                    out[idx] = acc[i][j][r] + bd[o] + x[idx];
                }
    }
}

extern "C" void kernel_launch(void* const* d_in, const int* in_sizes, int n_in,
                              void* d_out, int out_size, void* d_ws, size_t ws_size,
                              hipStream_t stream) {
    const float* x_ori = (const float*)d_in[0];
    const float* cross = (const float*)d_in[1];
    const float* Wp    = (const float*)d_in[2];
    const float* bp    = (const float*)d_in[3];
    const float* Wd    = (const float*)d_in[4];
    const float* bd    = (const float*)d_in[5];
    float* out = (float*)d_out;

    // ws: [0, 3,145,728): U bf16 [8][3072][64]
    //     [3,145,728, +131,072): G f32 [8][64][64] (zeroed in-kernel phase Z)
    u16*   U = (u16*)d_ws;
    float* G = (float*)((char*)d_ws + (size_t)BB * BCN * sizeof(u16));

    void* args[] = {(void*)&Wp, (void*)&cross, (void*)&bp, (void*)&x_ori,
                    (void*)&Wd, (void*)&bd, (void*)&U, (void*)&G, (void*)&out};
    hipLaunchCooperativeKernel(reinterpret_cast<void*>(k_all), dim3(384), dim3(256),
                               args, 0, stream);
}

// Round 4
// 117.830 us; speedup vs baseline: 2.2886x; 2.2886x over previous
//
#include <hip/hip_runtime.h>

typedef unsigned short u16;
typedef short bf16x8 __attribute__((ext_vector_type(8)));
typedef float f32x4 __attribute__((ext_vector_type(4)));

#define BB 8
#define CC 768
#define NN 256
#define HH 12
#define DD 64
#define K3 3072          // H*N
#define BCN 196608       // C*N per batch
#define SCALE 0.125f
#define LDP 72           // LDS pitch (u16): 144B rows, 16B-aligned, 2-way banks only

__device__ __forceinline__ u16 f2b(float f) {
    union { float f; unsigned int i; } v; v.f = f;
    unsigned int r = v.i + 0x7FFFu + ((v.i >> 16) & 1u);
    return (u16)(r >> 16);
}

// one 64x64x64 MFMA macro-step (4 waves, each 32x32, K=64 in two k-halves)
#define MFMA8(ASP, BSP, ACC)                                                              \
    _Pragma("unroll")                                                                     \
    for (int kk = 0; kk < 2; ++kk) {                                                      \
        bf16x8 a0 = *reinterpret_cast<bf16x8*>((ASP) + (wm + tx) * LDP + kk * 32 + q * 8);\
        bf16x8 a1 = *reinterpret_cast<bf16x8*>((ASP) + (wm + 16 + tx) * LDP + kk * 32 + q * 8);\
        bf16x8 b0 = *reinterpret_cast<bf16x8*>((BSP) + (wn + tx) * LDP + kk * 32 + q * 8);\
        bf16x8 b1 = *reinterpret_cast<bf16x8*>((BSP) + (wn + 16 + tx) * LDP + kk * 32 + q * 8);\
        ACC[0][0] = __builtin_amdgcn_mfma_f32_16x16x32_bf16(a0, b0, ACC[0][0], 0, 0, 0);  \
        ACC[0][1] = __builtin_amdgcn_mfma_f32_16x16x32_bf16(a0, b1, ACC[0][1], 0, 0, 0);  \
        ACC[1][0] = __builtin_amdgcn_mfma_f32_16x16x32_bf16(a1, b0, ACC[1][0], 0, 0, 0);  \
        ACC[1][1] = __builtin_amdgcn_mfma_f32_16x16x32_bf16(a1, b1, ACC[1][1], 0, 0, 0);  \
    }

// ---------------------------------------------------------------------------
// Stage 1: cp[b,o,n] = sum_c Wp[o,c]*cross[b,c,n] + bp[o]     (bf16 out)
// NT-MFMA 64x64x64 tiles, 12 K-iters with 1-deep register prefetch: iter k+1's
// global loads are issued right after iter k's regs->LDS writes, so HBM/L2
// latency hides under the transpose + MFMA phases. Blocks (0,0,b) zero G[b]
// (consumed by k_gram next dispatch — stream-ordered).
// ---------------------------------------------------------------------------
__global__ __launch_bounds__(256) void k_proj(
    const float* __restrict__ Wp, const float* __restrict__ cross,
    const float* __restrict__ bp, u16* __restrict__ cp, float* __restrict__ G)
{
    __shared__ __align__(16) u16 As[64 * LDP];
    __shared__ __align__(16) u16 Bs[64 * LDP];
    __shared__ __align__(16) float T[64][68];
    const int n0 = blockIdx.x * 64;
    const int o0 = blockIdx.y * 64;
    const int b  = blockIdx.z;
    const int t = threadIdx.x;
    const int lane = t & 63, wave = t >> 6;
    const int q = lane >> 4, tx = lane & 15;
    const int wm = (wave & 1) * 32, wn = (wave >> 1) * 32;
    const int r4 = t >> 2, cq = t & 3;

    if (blockIdx.x == 0 && blockIdx.y == 0) {   // zero G[b]
        float4 z = {0.f, 0.f, 0.f, 0.f};
        float* Gb = G + b * 4096;
        #pragma unroll
        for (int j = 0; j < 4; ++j)
            *reinterpret_cast<float4*>(Gb + t * 4 + j * 1024) = z;
    }

    const float* crb = cross + b * BCN;
    const float* wsrc = Wp + (o0 + r4) * CC;    // contiguous row o0+r4

    f32x4 acc[2][2] = {};
    float4 ra[4], rc[4];
    #pragma unroll
    for (int u = 0; u < 4; ++u) {               // prologue: iter-0 tiles -> regs
        const int cl = (cq + 4 * u) * 4;
        ra[u] = *reinterpret_cast<const float4*>(wsrc + cl);
        rc[u] = *reinterpret_cast<const float4*>(crb + r4 * NN + n0 + cl);
    }
    for (int it = 0; it < 12; ++it) {
        if (it > 0) __syncthreads();            // prev MFMA readers of As/Bs done
        {   // regs -> As (cvt) and T (f32)
            u16* dstA = As + r4 * LDP;
            #pragma unroll
            for (int u = 0; u < 4; ++u) {
                const int cl = (cq + 4 * u) * 4;
                ushort4 w; w.x = f2b(ra[u].x); w.y = f2b(ra[u].y);
                w.z = f2b(ra[u].z); w.w = f2b(ra[u].w);
                *reinterpret_cast<ushort4*>(dstA + cl) = w;
                T[r4][cl + 0] = rc[u].x; T[r4][cl + 1] = rc[u].y;
                T[r4][cl + 2] = rc[u].z; T[r4][cl + 3] = rc[u].w;
            }
        }
        if (it < 11) {   // issue next-iter loads; in flight across transpose+MFMA
            const int c0 = (it + 1) * 64;
            #pragma unroll
            for (int u = 0; u < 4; ++u) {
                const int cl = (cq + 4 * u) * 4;
                ra[u] = *reinterpret_cast<const float4*>(wsrc + c0 + cl);
                rc[u] = *reinterpret_cast<const float4*>(crb + (c0 + r4) * NN + n0 + cl);
            }
        }
        __syncthreads();
        {   // Bs[n][c] = cvt(T[c][n])  (transpose; T col reads are 2-way = free)
            const int nn = t >> 2, dq = t & 3;
            u16* dst = Bs + nn * LDP;
            #pragma unroll
            for (int u = 0; u < 4; ++u) {
                const int c4 = (dq + 4 * u) * 4;
                ushort4 w;
                w.x = f2b(T[c4 + 0][nn]); w.y = f2b(T[c4 + 1][nn]);
                w.z = f2b(T[c4 + 2][nn]); w.w = f2b(T[c4 + 3][nn]);
                *reinterpret_cast<ushort4*>(dst + c4) = w;
            }
        }
        __syncthreads();
        MFMA8(As, Bs, acc)
    }
    u16* cpb = cp + b * BCN;
    #pragma unroll
    for (int i = 0; i < 2; ++i)
        #pragma unroll
        for (int j = 0; j < 2; ++j)
            #pragma unroll
            for (int r = 0; r < 4; ++r) {
                const int o = o0 + wm + i * 16 + q * 4 + r;
                const int n = n0 + wn + j * 16 + tx;
                cpb[o * NN + n] = f2b(acc[i][j][r] + bp[o]);
            }
}

// ---------------------------------------------------------------------------
// Stage 2: G[b][dd][d] += SCALE * sum_k cross_view[dd][k]*cp_view[d][k]
// Split-K 48 x 64 chunks, f32 atomics (G pre-zeroed by k_proj). Unchanged (R0).
// ---------------------------------------------------------------------------
__global__ __launch_bounds__(256) void k_gram(
    const float* __restrict__ cross, const u16* __restrict__ cp, float* __restrict__ G)
{
    __shared__ __align__(16) u16 As[64 * LDP];
    __shared__ __align__(16) u16 Bs[64 * LDP];
    const int kb = blockIdx.x * 64;
    const int b  = blockIdx.y;
    const int t = threadIdx.x;
    const int lane = t & 63, wave = t >> 6;
    const int q = lane >> 4, tx = lane & 15;
    const int wm = (wave & 1) * 32, wn = (wave >> 1) * 32;
    const float* crb = cross + b * BCN;
    const u16* cpb = cp + b * BCN;
    f32x4 acc[2][2] = {};
    {
        const int r = t >> 2, cq = t & 3;
        const float* src = crb + r * K3 + kb;
        u16* dst = As + r * LDP;
        #pragma unroll
        for (int u = 0; u < 4; ++u) {
            const int cl = (cq + 4 * u) * 4;
            float4 v = *reinterpret_cast<const float4*>(src + cl);
            ushort4 w; w.x = f2b(v.x); w.y = f2b(v.y); w.z = f2b(v.z); w.w = f2b(v.w);
            *reinterpret_cast<ushort4*>(dst + cl) = w;
        }
    }
    {
        const int r = t >> 3, ch = (t & 7) * 8;
        *reinterpret_cast<uint4*>(Bs + r * LDP + ch) =
            *reinterpret_cast<const uint4*>(cpb + r * K3 + kb + ch);
        *reinterpret_cast<uint4*>(Bs + (r + 32) * LDP + ch) =
            *reinterpret_cast<const uint4*>(cpb + (r + 32) * K3 + kb + ch);
    }
    __syncthreads();
    MFMA8(As, Bs, acc)
    float* Gb = G + b * 4096;
    #pragma unroll
    for (int i = 0; i < 2; ++i)
        #pragma unroll
        for (int j = 0; j < 2; ++j)
            #pragma unroll
            for (int r = 0; r < 4; ++r) {
                const int dd = wm + i * 16 + q * 4 + r;
                const int d  = wn + j * 16 + tx;
                atomicAdd(Gb + dd * DD + d, acc[i][j][r] * SCALE);
            }
}

// ---------------------------------------------------------------------------
// Stage 3: U[b][m][dd] = sum_d xT[m][d]*G[dd][d].  Unchanged (R0).
// U (bf16) aliases cp. 48 m-tiles x 8 batches.
// ---------------------------------------------------------------------------
__global__ __launch_bounds__(256) void k_xm(
    const float* __restrict__ x, const float* __restrict__ G, u16* __restrict__ U)
{
    __shared__ __align__(16) u16 As[64 * LDP];
    __shared__ __align__(16) u16 Bs[64 * LDP];
    __shared__ __align__(16) float T[64][68];
    const int m0 = blockIdx.x * 64;
    const int b  = blockIdx.y;
    const int h   = m0 >> 8;       // head index (m = h*256 + nn)
    const int nn0 = m0 & 255;
    const int t = threadIdx.x;
    const int lane = t & 63, wave = t >> 6;
    const int q = lane >> 4, tx = lane & 15;
    const int wm = (wave & 1) * 32, wn = (wave >> 1) * 32;
    const float* xb = x + b * BCN;
    const float* Gb = G + b * 4096;
    f32x4 acc[2][2] = {};
    {   // T[d][nl] = x[(d*12+h)*256 + nn0+nl]  (coalesced rows)
        const int d = t >> 2, fq = t & 3;
        const float* src = xb + (d * HH + h) * NN + nn0;
        #pragma unroll
        for (int u = 0; u < 4; ++u) {
            const int nl = (fq + 4 * u) * 4;
            float4 v = *reinterpret_cast<const float4*>(src + nl);
            T[d][nl + 0] = v.x; T[d][nl + 1] = v.y; T[d][nl + 2] = v.z; T[d][nl + 3] = v.w;
        }
    }
    {   // Bs[dd][d] = cvt(G[dd][d])
        const int r = t >> 2, cq = t & 3;
        const float* src = Gb + r * DD;
        u16* dst = Bs + r * LDP;
        #pragma unroll
        for (int u = 0; u < 4; ++u) {
            const int cl = (cq + 4 * u) * 4;
            float4 v = *reinterpret_cast<const float4*>(src + cl);
            ushort4 w; w.x = f2b(v.x); w.y = f2b(v.y); w.z = f2b(v.z); w.w = f2b(v.w);
            *reinterpret_cast<ushort4*>(dst + cl) = w;
        }
    }
    __syncthreads();
    {   // As[m_local][d] = cvt(T[d][m_local])  (transpose)
        const int nn = t >> 2, dq = t & 3;
        u16* dst = As + nn * LDP;
        #pragma unroll
        for (int u = 0; u < 4; ++u) {
            const int d4 = (dq + 4 * u) * 4;
            ushort4 w;
            w.x = f2b(T[d4 + 0][nn]); w.y = f2b(T[d4 + 1][nn]);
            w.z = f2b(T[d4 + 2][nn]); w.w = f2b(T[d4 + 3][nn]);
            *reinterpret_cast<ushort4*>(dst + d4) = w;
        }
    }
    __syncthreads();
    MFMA8(As, Bs, acc)
    u16* Ub = U + b * BCN;
    #pragma unroll
    for (int i = 0; i < 2; ++i)
        #pragma unroll
        for (int j = 0; j < 2; ++j)
            #pragma unroll
            for (int r = 0; r < 4; ++r) {
                const int m  = m0 + wm + i * 16 + q * 4 + r;
                const int dd = wn + j * 16 + tx;
                Ub[m * DD + dd] = f2b(acc[i][j][r]);
            }
}

// ---------------------------------------------------------------------------
// Stage 4: out[b,o,n] = x[b,o,n] + bd[o] + sum_k Wd[o,k]*U2[n,k]
// A=Wd (f32 cvt), B=U2 = U flat viewed [256][768] (bf16, k-contig). Native NT.
// 12 K-iters with 1-deep register prefetch (same barrier count as R0; loads
// of iter k+1 in flight across sync+MFMA of iter k).
// ---------------------------------------------------------------------------
__global__ __launch_bounds__(256) void k_dep(
    const float* __restrict__ Wd, const u16* __restrict__ U,
    const float* __restrict__ bd, const float* __restrict__ x, float* __restrict__ out)
{
    __shared__ __align__(16) u16 As[64 * LDP];
    __shared__ __align__(16) u16 Bs[64 * LDP];
    const int n0 = blockIdx.x * 64;
    const int o0 = blockIdx.y * 64;
    const int b  = blockIdx.z;
    const int t = threadIdx.x;
    const int lane = t & 63, wave = t >> 6;
    const int q = lane >> 4, tx = lane & 15;
    const int wm = (wave & 1) * 32, wn = (wave >> 1) * 32;
    const int r4 = t >> 2, cq = t & 3;
    const int r8 = t >> 3, ch = (t & 7) * 8;
    const u16* Ub = U + b * BCN;
    const float* srcA0 = Wd + (o0 + r4) * CC;

    float4 ra[4]; uint4 rb[2];
    #pragma unroll
    for (int u = 0; u < 4; ++u)                 // prologue: iter-0 tiles -> regs
        ra[u] = *reinterpret_cast<const float4*>(srcA0 + (cq + 4 * u) * 4);
    rb[0] = *reinterpret_cast<const uint4*>(Ub + (n0 + r8) * CC + ch);
    rb[1] = *reinterpret_cast<const uint4*>(Ub + (n0 + r8 + 32) * CC + ch);

    f32x4 acc[2][2] = {};
    for (int it = 0; it < 12; ++it) {
        if (it > 0) __syncthreads();            // prev MFMA readers of As/Bs done
        {   // regs -> LDS
            u16* dst = As + r4 * LDP;
            #pragma unroll
            for (int u = 0; u < 4; ++u) {
                const int cl = (cq + 4 * u) * 4;
                ushort4 w; w.x = f2b(ra[u].x); w.y = f2b(ra[u].y);
                w.z = f2b(ra[u].z); w.w = f2b(ra[u].w);
                *reinterpret_cast<ushort4*>(dst + cl) = w;
            }
            *reinterpret_cast<uint4*>(Bs + r8 * LDP + ch) = rb[0];
            *reinterpret_cast<uint4*>(Bs + (r8 + 32) * LDP + ch) = rb[1];
        }
        if (it < 11) {   // issue next-iter loads; in flight across sync+MFMA
            const int c0 = (it + 1) * 64;
            #pragma unroll
            for (int u = 0; u < 4; ++u)
                ra[u] = *reinterpret_cast<const float4*>(srcA0 + c0 + (cq + 4 * u) * 4);
            rb[0] = *reinterpret_cast<const uint4*>(Ub + (n0 + r8) * CC + c0 + ch);
            rb[1] = *reinterpret_cast<const uint4*>(Ub + (n0 + r8 + 32) * CC + c0 + ch);
        }
        __syncthreads();
        MFMA8(As, Bs, acc)
    }
    #pragma unroll
    for (int i = 0; i < 2; ++i)
        #pragma unroll
        for (int j = 0; j < 2; ++j)
            #pragma unroll
            for (int r = 0; r < 4; ++r) {
                const int o = o0 + wm + i * 16 + q * 4 + r;
                const int n = n0 + wn + j * 16 + tx;
                const int idx = b * BCN + o * NN + n;
                out[idx] = acc[i][j][r] + bd[o] + x[idx];
            }
}

extern "C" void kernel_launch(void* const* d_in, const int* in_sizes, int n_in,
                              void* d_out, int out_size, void* d_ws, size_t ws_size,
                              hipStream_t stream) {
    const float* x_ori = (const float*)d_in[0];
    const float* cross = (const float*)d_in[1];
    const float* Wp    = (const float*)d_in[2];
    const float* bp    = (const float*)d_in[3];
    const float* Wd    = (const float*)d_in[4];
    const float* bd    = (const float*)d_in[5];
    float* out = (float*)d_out;

    // ws: [0, 3,145,728): cp bf16 [8][768][256]; ALIASED by U bf16
    //     [8][3072][64] after k_gram (cp dead, stream-serialized).
    //     [3,145,728, +131,072): G f32 [8][64][64] (zeroed by k_proj blocks).
    u16*   cp = (u16*)d_ws;
    u16*   U  = (u16*)d_ws;
    float* G  = (float*)((char*)d_ws + (size_t)BB * BCN * sizeof(u16));

    k_proj<<<dim3(4, 12, BB), 256, 0, stream>>>(Wp, cross, bp, cp, G);
    k_gram<<<dim3(48, BB), 256, 0, stream>>>(cross, cp, G);
    k_xm  <<<dim3(48, BB), 256, 0, stream>>>(x_ori, G, U);
    k_dep <<<dim3(4, 12, BB), 256, 0, stream>>>(Wd, U, bd, x_ori, out);
}